// Round 9
// baseline (23538.707 us; speedup 1.0000x reference)
//
#include <hip/hip_runtime.h>
#include <hip/hip_cooperative_groups.h>
#include <math.h>

namespace cg = cooperative_groups;

// SRNN: T=128, B=256, D=512, H=1024, O=20
// v_new = ALPHA*v + z@Wrec_eff^T + x_t@Win^T - z*THR ; z_new = v_new > THR
// vo_new = KAPPA*vo + z_new@Wout^T ; out = softmax(vo, axis=2)
//
// ORDER CONTRACT (validated R6/R7/R8 — DO NOT BREAK):
//   P (K=1024): ((c[0,320)+c[320,640))+c[640,960))+c[960,1024)
//   Q (K=512) :   c[0,320)+c[320,512)
//   per-chunk: single sequential ascending-k fma chain per element
//   elementwise: ((ALPHA_f32*v + P) + Q) - z   (all _rn, left-assoc)
//   diag as z*0 in-chain (WrecT diag pre-zeroed; fma(z,0,acc)==acc+z*0)
// R9: ONE persistent cooperative kernel runs all 127 steps (replaces 254
// launch nodes with 254 grid.sync()s). Phase A = chunk FMA (R8 body,
// bit-identical); Phase B = combine+pack on blocks 0..255. v[b] stays
// block-local (same block reads/writes it every step); part/zhist cross
// blocks and are ordered by threadfence + grid.sync. Readout stays deferred.

#define T_ 128
#define B_ 256
#define D_ 512
#define H_ 1024
#define O_ 20
#define ST_ 127
#define WPB 32
#define ALPHA_F ((float)0.95122942450071400909)
#define KAPPA_F ((float)0.95122942450071400909)

typedef float v2f __attribute__((ext_vector_type(2)));

#if defined(__has_builtin)
#if __has_builtin(__builtin_elementwise_fma)
#define PK_FMA(a, b, c) __builtin_elementwise_fma(a, b, c)
#endif
#endif
#ifndef PK_FMA
static __device__ inline v2f pk_fma_impl(v2f a, v2f b, v2f c) {
    v2f r; r[0] = __fmaf_rn(a[0], b[0], c[0]); r[1] = __fmaf_rn(a[1], b[1], c[1]);
    return r;
}
#define PK_FMA(a, b, c) pk_fma_impl(a, b, c)
#endif

// ------------------------------------------------------------ transpose ----
__global__ __launch_bounds__(256) void transpose_k(
    const float* __restrict__ src, float* __restrict__ dst,
    int rows, int cols, int zero_diag)
{
    __shared__ float tile[32][33];
    const int c0 = blockIdx.x * 32;
    const int r0 = blockIdx.y * 32;
    const int tid = threadIdx.x;
    const int lr = tid >> 3;
    const int lc = (tid & 7) * 4;
    const float4 vv = *(const float4*)(src + (size_t)(r0 + lr) * cols + c0 + lc);
    tile[lr][lc+0] = vv.x; tile[lr][lc+1] = vv.y;
    tile[lr][lc+2] = vv.z; tile[lr][lc+3] = vv.w;
    __syncthreads();
    const int wc = lr;
    const int wr = lc;
    float4 o;
    o.x = tile[wr+0][wc]; o.y = tile[wr+1][wc];
    o.z = tile[wr+2][wc]; o.w = tile[wr+3][wc];
    if (zero_diag) {
        const int c = c0 + wc;
        if (c == r0 + wr + 0) o.x = 0.f;
        if (c == r0 + wr + 1) o.y = 0.f;
        if (c == r0 + wr + 2) o.z = 0.f;
        if (c == r0 + wr + 3) o.w = 0.f;
    }
    *(float4*)(dst + (size_t)(c0 + wc) * rows + r0 + wr) = o;
}

// ---------------------------------------------------------------- init ----
__global__ __launch_bounds__(256) void srnn_init(
    float* __restrict__ v, unsigned* __restrict__ z0)
{
    const int i = blockIdx.x * 256 + threadIdx.x;
    if (i < B_ * H_)  v[i]  = 0.0f;
    if (i < B_ * WPB) z0[i] = 0u;
}

// -------------------------------------------- persistent step kernel ------
// 384 blocks (cooperative). Roles as R8: heavy (320-k) blocks 0..255 =
// {P0,P1,P2,Q0}x64 tiles; 256..319 = Q1 (192-k); 320..383 = P3 (64-k).
// Per step: phase A chunk FMA -> part; grid.sync; phase B (blocks 0..255)
// combine+spike-pack -> v, zhist[s]; grid.sync.
__global__ __launch_bounds__(256, 2) void srnn_persist(
    const float* __restrict__ x,        // [T,B,D]
    const float* __restrict__ WrecT,    // [1024k][1024h], diag zeroed
    const float* __restrict__ WinT,     // [512k][1024h]
    const unsigned* __restrict__ z0,    // [B,WPB] zeros
    unsigned* __restrict__ zhist,       // [ST][B][WPB]
    float* __restrict__ part,           // [6][B,H]
    float* __restrict__ v)              // [B,H]
{
    cg::grid_group grid = cg::this_grid();

    __shared__ float wt[32][68];        // [k][h]
    __shared__ float zt[32][68];        // [k][b]
    __shared__ unsigned zw_sh[WPB];

    const int bid = blockIdx.x;
    const int tid = threadIdx.x;

    int slot, t0, t1;
    const float* WT;
    bool rec;
    if (bid < 256) {
        const int hc = bid >> 6;
        if      (hc == 0) { slot = 0; t0 = 0;  t1 = 10; WT = WrecT; rec = true;  }
        else if (hc == 1) { slot = 1; t0 = 10; t1 = 20; WT = WrecT; rec = true;  }
        else if (hc == 2) { slot = 2; t0 = 20; t1 = 30; WT = WrecT; rec = true;  }
        else              { slot = 4; t0 = 0;  t1 = 10; WT = WinT;  rec = false; }
    } else if (bid < 320) { slot = 5; t0 = 10; t1 = 16; WT = WinT;  rec = false; }
    else                  { slot = 3; t0 = 30; t1 = 32; WT = WrecT; rec = true;  }

    const int t  = bid & 63;
    const int h0 = (t & 15) << 6;
    const int b0 = (t >> 4) << 6;
    const int tx4 = (tid & 15) << 2;    // 4 consecutive h
    const int ty4 = (tid >> 4) << 2;    // 4 consecutive b
    const int zb = tid & 63;            // local b (z staging)
    const int kg = tid >> 6;            // 8-bit group (z staging)
    float* pdst = part + (size_t)slot * (B_ * H_);

    for (int s = 0; s < ST_; ++s) {
        const unsigned* zin = (s == 0) ? z0
                            : (zhist + (size_t)(s - 1) * B_ * WPB);

        // ------------------------------ phase A: chunk matmul -> part ----
        v2f acc[4][2];
        #pragma unroll
        for (int i = 0; i < 4; ++i) { acc[i][0] = (v2f)0.f; acc[i][1] = (v2f)0.f; }

        const float* xs = x + (size_t)s * (B_ * D_);

        for (int kc = t0; kc < t1; ++kc) {
            #pragma unroll
            for (int q = 0; q < 2; ++q) {
                const int idx = tid * 2 + q;
                const int r = idx >> 4, c4 = (idx & 15) << 2;
                *(float4*)&wt[r][c4] =
                    *(const float4*)(WT + (size_t)(kc * 32 + r) * H_ + h0 + c4);
            }
            if (rec) {
                const unsigned zw = zin[(size_t)(b0 + zb) * WPB + kc];
                #pragma unroll
                for (int j = 0; j < 8; ++j)
                    zt[kg * 8 + j][zb] = (float)((zw >> (kg * 8 + j)) & 1u);
            } else {
                #pragma unroll
                for (int q = 0; q < 2; ++q) {
                    const int idx = tid * 2 + q;
                    const int br = idx >> 3, kq = (idx & 7) << 2;
                    const float4 xv =
                        *(const float4*)(xs + (size_t)(b0 + br) * D_ + kc * 32 + kq);
                    zt[kq+0][br] = xv.x; zt[kq+1][br] = xv.y;
                    zt[kq+2][br] = xv.z; zt[kq+3][br] = xv.w;
                }
            }
            __syncthreads();
            #pragma unroll
            for (int kk = 0; kk < 32; ++kk) {       // k ascending — contract
                const float4 zf = *(const float4*)&zt[kk][ty4];
                const float4 wf = *(const float4*)&wt[kk][tx4];
                v2f wlo, whi;
                wlo[0] = wf.x; wlo[1] = wf.y;
                whi[0] = wf.z; whi[1] = wf.w;
                const float zz[4] = {zf.x, zf.y, zf.z, zf.w};
                #pragma unroll
                for (int i = 0; i < 4; ++i) {
                    v2f zv; zv[0] = zz[i]; zv[1] = zz[i];
                    acc[i][0] = PK_FMA(zv, wlo, acc[i][0]);
                    acc[i][1] = PK_FMA(zv, whi, acc[i][1]);
                }
            }
            __syncthreads();
        }

        #pragma unroll
        for (int i = 0; i < 4; ++i) {
            float4 o;
            o.x = acc[i][0][0]; o.y = acc[i][0][1];
            o.z = acc[i][1][0]; o.w = acc[i][1][1];
            *(float4*)(pdst + (size_t)(b0 + ty4 + i) * H_ + h0 + tx4) = o;
        }

        __threadfence();
        grid.sync();

        // --------------------- phase B: combine + spike pack (b = bid) ----
        if (bid < 256) {
            const int b = bid;
            unsigned* zout = zhist + (size_t)s * B_ * WPB;
            const int h4 = tid * 4;
            const size_t bh = (size_t)b * H_ + h4;
            const size_t BH = (size_t)B_ * H_;

            const float4 p0 = *(const float4*)(part + 0*BH + bh);
            const float4 p1 = *(const float4*)(part + 1*BH + bh);
            const float4 p2 = *(const float4*)(part + 2*BH + bh);
            const float4 p3 = *(const float4*)(part + 3*BH + bh);
            const float4 q0 = *(const float4*)(part + 4*BH + bh);
            const float4 q1 = *(const float4*)(part + 5*BH + bh);
            const float4 vold = *(const float4*)(v + bh);
            const unsigned zword = zin[(size_t)b * WPB + (tid >> 3)];

            const float pp0[4] = {p0.x, p0.y, p0.z, p0.w};
            const float pp1[4] = {p1.x, p1.y, p1.z, p1.w};
            const float pp2[4] = {p2.x, p2.y, p2.z, p2.w};
            const float pp3[4] = {p3.x, p3.y, p3.z, p3.w};
            const float qq0[4] = {q0.x, q0.y, q0.z, q0.w};
            const float qq1[4] = {q1.x, q1.y, q1.z, q1.w};
            const float vv4[4] = {vold.x, vold.y, vold.z, vold.w};

            float vn4[4];
            unsigned nib = 0u;
            #pragma unroll
            for (int m = 0; m < 4; ++m) {
                const float P = __fadd_rn(__fadd_rn(__fadd_rn(pp0[m], pp1[m]), pp2[m]), pp3[m]);
                const float Q = __fadd_rn(qq0[m], qq1[m]);
                const float zs = ((zword >> (((tid & 7) << 2) + m)) & 1u) ? 1.f : 0.f;
                const float t1e = __fmul_rn(ALPHA_F, vv4[m]);
                const float t2e = __fadd_rn(t1e, P);
                const float t3e = __fadd_rn(t2e, Q);
                const float vn = __fsub_rn(t3e, zs);
                vn4[m] = vn;
                if (vn > 1.0f) nib |= (1u << m);
            }
            float4 vst; vst.x = vn4[0]; vst.y = vn4[1]; vst.z = vn4[2]; vst.w = vn4[3];
            *(float4*)(v + bh) = vst;

            if (tid < WPB) zw_sh[tid] = 0u;
            __syncthreads();
            if (nib) atomicOr(&zw_sh[tid >> 3], nib << ((tid & 7) << 2));
            __syncthreads();
            if (tid < WPB) zout[(size_t)b * WPB + tid] = zw_sh[tid];
        }

        __threadfence();
        grid.sync();
    }
}

// --------------------------------------------- deferred readout: zo ------
__global__ __launch_bounds__(256) void srnn_zo(
    const unsigned* __restrict__ zhist, // [ST][B][WPB]
    const float* __restrict__ w_out,    // [O,H]
    float* __restrict__ zo)             // [ST][B][O]
{
    __shared__ float red[16][16][O_ + 1];
    const int s  = blockIdx.x >> 4;
    const int bg = blockIdx.x & 15;
    const int tid = threadIdx.x;
    const int bl  = tid >> 4;
    const int seg = tid & 15;
    const int b = bg * 16 + bl;
    const unsigned* zr = zhist + ((size_t)s * B_ + b) * WPB;
    const unsigned w0 = zr[seg * 2 + 0];
    const unsigned w1 = zr[seg * 2 + 1];

    float a[O_];
    #pragma unroll
    for (int o = 0; o < O_; ++o) a[o] = 0.f;
    const int hb = seg * 64;
    for (int j = 0; j < 32; ++j) {
        if ((w0 >> j) & 1u) {
            #pragma unroll
            for (int o = 0; o < O_; ++o) a[o] += w_out[(size_t)o * H_ + hb + j];
        }
    }
    for (int j = 0; j < 32; ++j) {
        if ((w1 >> j) & 1u) {
            #pragma unroll
            for (int o = 0; o < O_; ++o) a[o] += w_out[(size_t)o * H_ + hb + 32 + j];
        }
    }
    #pragma unroll
    for (int o = 0; o < O_; ++o) red[bl][seg][o] = a[o];
    __syncthreads();
    for (int w = tid; w < 16 * O_; w += 256) {
        const int bl2 = w / O_, o = w % O_;
        float sum = 0.f;
        #pragma unroll
        for (int g = 0; g < 16; ++g) sum += red[bl2][g][o];
        zo[((size_t)s * B_ + bg * 16 + bl2) * O_ + o] = sum;
    }
}

// --------------------------------------- kappa-scan + softmax (fp32) -----
__global__ __launch_bounds__(64) void srnn_scan(
    const float* __restrict__ zo,   // [ST][B][O]
    float* __restrict__ out)        // [T][B][O]
{
    __shared__ float vos[T_][O_];
    const int b = blockIdx.x;
    const int tid = threadIdx.x;
    if (tid < O_) {
        float vo = 0.f;
        vos[0][tid] = 0.f;          // vo[0] stays zero
        for (int sp = 0; sp < ST_; ++sp) {
            vo = KAPPA_F * vo + zo[((size_t)sp * B_ + b) * O_ + tid];
            vos[sp + 1][tid] = vo;
        }
    }
    __syncthreads();
    for (int t = tid; t < T_; t += 64) {
        float m = -1e30f;
        #pragma unroll
        for (int o = 0; o < O_; ++o) m = fmaxf(m, vos[t][o]);
        float e[O_];
        float ssum = 0.f;
        #pragma unroll
        for (int o = 0; o < O_; ++o) {
            const float ee = expf(vos[t][o] - m);
            e[o] = ee;
            ssum += ee;
        }
        const float inv = 1.f / ssum;
        #pragma unroll
        for (int o = 0; o < O_; ++o)
            out[((size_t)t * B_ + b) * O_ + o] = e[o] * inv;
    }
}

extern "C" void kernel_launch(void* const* d_in, const int* in_sizes, int n_in,
                              void* d_out, int out_size, void* d_ws, size_t ws_size,
                              hipStream_t stream) {
    const float* x     = (const float*)d_in[0];   // [128,256,512]
    const float* w_in  = (const float*)d_in[1];   // [1024,512]
    const float* w_rec = (const float*)d_in[2];   // [1024,1024]
    const float* w_out = (const float*)d_in[3];   // [20,1024]
    float* out = (float*)d_out;                   // [128,256,20]

    // ws layout (~19.8 MB): WrecT | WinT | part[6] | v | z0 | zhist | zo
    float*    WrecT = (float*)d_ws;                          // 4 MB
    float*    WinT  = WrecT + (size_t)H_ * H_;               // 2 MB
    float*    part  = WinT  + (size_t)D_ * H_;               // 6 MB
    float*    v     = part  + (size_t)6 * B_ * H_;           // 1 MB
    unsigned* z0    = (unsigned*)(v + (size_t)B_ * H_);      // 32 KB
    unsigned* zhist = z0 + (size_t)B_ * WPB;                 // 4.15 MB
    float*    zo    = (float*)(zhist + (size_t)ST_ * B_ * WPB); // 2.6 MB

    transpose_k<<<dim3(32, 32), 256, 0, stream>>>(w_rec, WrecT, H_, H_, 1);
    transpose_k<<<dim3(16, 32), 256, 0, stream>>>(w_in,  WinT,  H_, D_, 0);
    srnn_init<<<(B_ * H_ + 255) / 256, 256, 0, stream>>>(v, z0);

    void* args[] = { (void*)&x, (void*)&WrecT, (void*)&WinT, (void*)&z0,
                     (void*)&zhist, (void*)&part, (void*)&v };
    hipLaunchCooperativeKernel((const void*)srnn_persist,
                               dim3(384), dim3(256), args, 0, stream);

    srnn_zo<<<ST_ * 16, 256, 0, stream>>>(zhist, w_out, zo);
    srnn_scan<<<B_, 64, 0, stream>>>(zo, out);
}